// Round 11
// baseline (143.121 us; speedup 1.0000x reference)
//
#include <hip/hip_runtime.h>

// EncoderLayer: B=4, S=2048, D=512, H=8, HD=64. fp32 I/O, bf16 MFMA compute.
// M = B*S = 8192 tokens. GEMMs: [8192,512] = [8192,512] @ W[512,512]^T.

typedef short s16x8 __attribute__((ext_vector_type(8)));
typedef float f32x4 __attribute__((ext_vector_type(4)));
typedef unsigned short u16;
typedef u16 u16x4 __attribute__((ext_vector_type(4)));

__device__ __forceinline__ u16 f2b(float f) {          // fp32 -> bf16 RNE
  union { float f; unsigned u; } c; c.f = f;
  return (u16)((c.u + 0x7FFFu + ((c.u >> 16) & 1u)) >> 16);
}

__device__ __forceinline__ f32x4 mfma16(s16x8 a, s16x8 b, f32x4 c) {
  return __builtin_amdgcn_mfma_f32_16x16x32_bf16(a, b, c, 0, 0, 0);
}

// async global->LDS, 16B per lane; dest = wave-uniform base + lane*16
__device__ __forceinline__ void gload_lds16(const u16* g, u16* l) {
  __builtin_amdgcn_global_load_lds(
      (const __attribute__((address_space(1))) unsigned*)g,
      (__attribute__((address_space(3))) unsigned*)l, 16, 0, 0);
}

// ---------------- weight cast: 6 x [512x512] fp32 -> bf16 (contiguous dst) --
// R11: weight stores NON-TEMPORAL. Theory (survives R4-R10 eliminations):
// QKV gemms read wq/wk/wv 2-3 dispatches after cast_w wrote them -> lines
// still DIRTY in remote XCD L2s (only LN1's traffic in between, not enough
// to evict 3MB from 32MB). A dirty line lives in ONE L2; each weight line is
// re-read by 64 blocks, 7/8 cross-die -> 64x dirty-service penalty at the
// observed ~700GB/s ceiling. W-zone gemms read the SAME buffer ~100us +
// ~65MB of evictions later -> clean L3 lines, locally cacheable -> 8.5us.
// (R10 falsified the A-input variant: LN-nt HURT, and WO reads fresh-dirty
// at_b fast -- A lines are single-read, weights are 64x-read.) nt streams
// cast's stores past L2 so all consumers see clean lines from the start.
__global__ __launch_bounds__(256) void cast_w(
    const float* __restrict__ s0, const float* __restrict__ s1,
    const float* __restrict__ s2, const float* __restrict__ s3,
    const float* __restrict__ s4, const float* __restrict__ s5,
    u16* __restrict__ dst)
{
  int i = blockIdx.x * 256 + threadIdx.x;   // float4 index, 65536 per matrix
  const float* s;
  switch (blockIdx.y) {
    case 0: s = s0; break; case 1: s = s1; break; case 2: s = s2; break;
    case 3: s = s3; break; case 4: s = s4; break; default: s = s5; break;
  }
  float4 v = ((const float4*)s)[i];
  u16x4 o; o.x = f2b(v.x); o.y = f2b(v.y); o.z = f2b(v.z); o.w = f2b(v.w);
  __builtin_nontemporal_store(
      o, (u16x4*)(dst + (size_t)blockIdx.y * 262144 + (size_t)i * 4));
}

// ---------------- LayerNorm (torch: unbiased var, a*(x-mean)/(std+eps)+b) ---
// R11: nt stores REVERTED (R10: +4.2us -- consumers lost the L2 hit; fresh-
// dirty A-tiles are fine since each A line is read exactly once).
template<int OF, int OB>
__global__ __launch_bounds__(256) void ln_kernel(
    const float* __restrict__ x, const float* __restrict__ ga,
    const float* __restrict__ gbv, float* __restrict__ yf, u16* __restrict__ yb)
{
  int row = blockIdx.x * 4 + (threadIdx.x >> 6);   // one wave per row
  int lane = threadIdx.x & 63;
  size_t base = (size_t)row * 512 + lane * 8;
  const float4* xr = (const float4*)(x + base);
  float4 v0 = xr[0], v1 = xr[1];
  float s  = v0.x + v0.y + v0.z + v0.w + v1.x + v1.y + v1.z + v1.w;
  float ss = v0.x*v0.x + v0.y*v0.y + v0.z*v0.z + v0.w*v0.w
           + v1.x*v1.x + v1.y*v1.y + v1.z*v1.z + v1.w*v1.w;
  #pragma unroll
  for (int m = 1; m < 64; m <<= 1) { s += __shfl_xor(s, m); ss += __shfl_xor(ss, m); }
  float mean = s * (1.0f / 512.0f);
  float var  = fmaxf((ss - 512.0f * mean * mean) * (1.0f / 511.0f), 0.0f);
  float inv  = 1.0f / (sqrtf(var) + 1e-6f);
  const float4* ap = (const float4*)(ga + lane * 8);
  const float4* bp = (const float4*)(gbv + lane * 8);
  float4 a0 = ap[0], a1 = ap[1], b0 = bp[0], b1 = bp[1];
  float4 y0, y1;
  y0.x = (v0.x-mean)*inv*a0.x + b0.x;  y0.y = (v0.y-mean)*inv*a0.y + b0.y;
  y0.z = (v0.z-mean)*inv*a0.z + b0.z;  y0.w = (v0.w-mean)*inv*a0.w + b0.w;
  y1.x = (v1.x-mean)*inv*a1.x + b1.x;  y1.y = (v1.y-mean)*inv*a1.y + b1.y;
  y1.z = (v1.z-mean)*inv*a1.z + b1.z;  y1.w = (v1.w-mean)*inv*a1.w + b1.w;
  if (OF) { float4* o = (float4*)(yf + base); o[0] = y0; o[1] = y1; }
  if (OB) {
    union { s16x8 v; u16 u[8]; } pk;
    pk.u[0]=f2b(y0.x); pk.u[1]=f2b(y0.y); pk.u[2]=f2b(y0.z); pk.u[3]=f2b(y0.w);
    pk.u[4]=f2b(y1.x); pk.u[5]=f2b(y1.y); pk.u[6]=f2b(y1.z); pk.u[7]=f2b(y1.w);
    *(s16x8*)(yb + base) = pk.v;
  }
}

// ---------------- GEMM 128x128 tile, BK=64 (8 K-iterations) -----------------
// 4 waves (2x2), each owns 64x64. LDS: 2 x (16KB A + 16KB B), 1 block/CU.
// Row = 8 chunks of 8 u16; swizzle chunk ^= (row&7) on staging source +
// ds_read (2-way = free). V^T epilogue window-blocked [B*W][nn][32]
// (W = sidx/32): one wave store instruction = 1KB contiguous.
// MODE bits: 1=bias, 2=relu, 4=resid(fp32), 8=store f32, 16=store bf16,
//            32=scale by qscale before bf16 store, 128=V^T window epilogue
template<int MODE>
__global__ __launch_bounds__(256) void gemm128(
    const u16* __restrict__ A, const u16* __restrict__ W,
    const float* __restrict__ bias, const float* __restrict__ resid,
    float* __restrict__ outf, u16* __restrict__ outb,
    u16* __restrict__ outb3, float qscale)
{
  __shared__ u16 als[2][128 * 64];             // 16KB per buf
  __shared__ u16 bls[2][128 * 64];
  int t = threadIdx.x, lane = t & 63, w = t >> 6;
  int l15 = lane & 15, g = lane >> 4;
  int wr = w >> 1, wc = w & 1;
  int mbase = blockIdx.x * 128, nbase = blockIdx.y * 128;

  // staging: instr j covers slots [j*256, j*256+256); slot cid -> row=cid>>3,
  // phys chunk cid&7, source (logical) chunk = (cid&7) ^ (row&7)
  size_t offA[4], offB[4];
  #pragma unroll
  for (int j = 0; j < 4; ++j) {
    int cid = j * 256 + t;
    int row = cid >> 3, cs = (cid & 7) ^ (row & 7);
    offA[j] = (size_t)(mbase + row) * 512 + cs * 8;
    offB[j] = (size_t)(nbase + row) * 512 + cs * 8;
  }

  #define GSTAGE(buf, k0) do {                                        \
    _Pragma("unroll")                                                 \
    for (int j = 0; j < 4; ++j)                                       \
      gload_lds16(A + (k0) + offA[j], &als[buf][(j * 256 + w * 64) * 8]); \
    _Pragma("unroll")                                                 \
    for (int j = 0; j < 4; ++j)                                       \
      gload_lds16(W + (k0) + offB[j], &bls[buf][(j * 256 + w * 64) * 8]); \
  } while (0)

  // fragment ds_read offsets (u16 units): row rA, logical chunk kh*4+g,
  // phys chunk = logical ^ (rA&7)
  int ar[4][2], br[4][2];
  #pragma unroll
  for (int i = 0; i < 4; ++i) {
    int rA = wr * 64 + i * 16 + l15;
    int rB = wc * 64 + i * 16 + l15;
    #pragma unroll
    for (int kh = 0; kh < 2; ++kh) {
      ar[i][kh] = rA * 64 + (((kh * 4 + g) ^ (rA & 7)) << 3);
      br[i][kh] = rB * 64 + (((kh * 4 + g) ^ (rB & 7)) << 3);
    }
  }

  f32x4 zero = {0.0f, 0.0f, 0.0f, 0.0f};
  f32x4 acc[4][4];
  #pragma unroll
  for (int mi = 0; mi < 4; ++mi)
    #pragma unroll
    for (int ni = 0; ni < 4; ++ni) acc[mi][ni] = zero;

  GSTAGE(0, 0);
  __syncthreads();
  int cur = 0;
  for (int kk = 0; kk < 8; ++kk) {
    if (kk < 7) GSTAGE(cur ^ 1, (kk + 1) * 64);    // prefetch next K-tile
    s16x8 af[4][2], bfr[4][2];
    #pragma unroll
    for (int i = 0; i < 4; ++i) {
      #pragma unroll
      for (int kh = 0; kh < 2; ++kh) {
        af[i][kh]  = *(const s16x8*)&als[cur][ar[i][kh]];
        bfr[i][kh] = *(const s16x8*)&bls[cur][br[i][kh]];
      }
    }
    #pragma unroll
    for (int kh = 0; kh < 2; ++kh)
      #pragma unroll
      for (int mi = 0; mi < 4; ++mi)
        #pragma unroll
        for (int ni = 0; ni < 4; ++ni)
          acc[mi][ni] = mfma16(af[mi][kh], bfr[ni][kh], acc[mi][ni]);
    __syncthreads();                               // prefetch landed, reads done
    cur ^= 1;
  }
  #undef GSTAGE

  if (MODE & 128) {
    // ---- V^T window-blocked epilogue: addr = ((b*64+W)*512+nn)*32 + pos ----
    // pos = 8g + 2r + (mi&1); one wave instruction = 1KB contiguous, 1 page.
    int bidx = mbase >> 11;
    int Wbase = ((mbase & 2047) >> 5) + wr * 2;    // window of sidx = m&2047
    #pragma unroll
    for (int ni = 0; ni < 4; ++ni) {
      int nn = nbase + wc * 64 + ni * 16 + l15;
      #pragma unroll
      for (int p = 0; p < 2; ++p) {            // mi-pair (2p, 2p+1)
        union { s16x8 v; u16 u[8]; } pkv;
        #pragma unroll
        for (int r = 0; r < 4; ++r) {
          pkv.u[2 * r]     = f2b(acc[2 * p][ni][r]);
          pkv.u[2 * r + 1] = f2b(acc[2 * p + 1][ni][r]);
        }
        *(s16x8*)(outb3 + ((size_t)((bidx * 64 + Wbase + p) * 512 + nn)) * 32
                  + 8 * g) = pkv.v;
      }
    }
  } else {
    #pragma unroll
    for (int ni = 0; ni < 4; ++ni) {
      int n = nbase + wc * 64 + ni * 16 + l15;
      float bv = (MODE & 1) ? bias[n] : 0.0f;
      #pragma unroll
      for (int mi = 0; mi < 4; ++mi) {
        #pragma unroll
        for (int r = 0; r < 4; ++r) {
          int m = mbase + wr * 64 + mi * 16 + 4 * g + r;  // D: col=l15, row=4g+r
          float v = acc[mi][ni][r] + bv;
          if (MODE & 2) v = fmaxf(v, 0.0f);
          if (MODE & 4) v += resid[(size_t)m * 512 + n];
          if (MODE & 8) outf[(size_t)m * 512 + n] = v;
          if (MODE & 16) {
            float vs = (MODE & 32) ? v * qscale : v;
            outb[(size_t)m * 512 + n] = f2b(vs);
          }
        }
      }
    }
  }
}

// ---------------- flash attention: QK^T-ahead software pipeline -------------
// 1 block = 128 q rows of one (b,h); 4 waves x 32 q rows (2 x 16-row frags).
// KVTILE=64. QK^T(kt+1) computed in the same scheduling region as
// softmax(kt)+PV(kt) so trans/LDS/MFMA overlap. 4 LDS buffers, 2-deep
// counted vmcnt prefetch. V staged from the window-blocked layout; LDS tile
// content bit-identical to the [B*n][S] variant, so PV math untouched.
// Swapped QK^T: mfma(K,Q) -> P lane-local in PV A-frag layout; no online max
// (q pre-scaled by 0.125*log2e, |s|<~2 in log2 domain, exp2 overflow at 127).
__global__ __launch_bounds__(256) void attn_kernel(
    const u16* __restrict__ q, const u16* __restrict__ k,
    const u16* __restrict__ vt, u16* __restrict__ o)
{
  __shared__ u16 kls[4][64 * 64];              // 8KB per buf, 64KB total
  __shared__ u16 vls[4][64 * 64];
  int t = threadIdx.x, lane = t & 63, w = t >> 6;
  int l15 = lane & 15, g = lane >> 4;
  int sw = l15 & 7;                            // ds_read swizzle key
  int lrow = lane >> 3;                        // staging: local row 0..7
  int lchunk = (lane & 7) ^ (lrow & 7);        // staging: pre-swizzled chunk
  // XCD-aware remap: each XCD sees 4 (b,h) pairs -> K/V L2-resident
  int fid = blockIdx.x + 32 * blockIdx.y;      // 0..511
  int xcd = fid & 7, rest = fid >> 3;
  int bh = xcd * 4 + (rest & 3);
  int qt = rest >> 2;                          // 0..15, q-tile of 128
  int bb = bh >> 3, h = bh & 7;
  int qbase = qt * 128 + w * 32;

  const u16* qp = q + (size_t)(bb * 2048 + qbase + l15) * 512 + h * 64 + g * 8;
  s16x8 qf0a = *(const s16x8*)qp;              // B-frag: lane&15 = q row
  s16x8 qf1a = *(const s16x8*)(qp + 32);
  s16x8 qf0b = *(const s16x8*)(qp + 16 * 512); // q-group 1: rows +16
  s16x8 qf1b = *(const s16x8*)(qp + 16 * 512 + 32);
  f32x4 zero = {0.0f, 0.0f, 0.0f, 0.0f};
  f32x4 oacc[2][4];
  #pragma unroll
  for (int qg = 0; qg < 2; ++qg)
    #pragma unroll
    for (int nf = 0; nf < 4; ++nf) oacc[qg][nf] = zero;
  float lsum[2] = {0.0f, 0.0f};                // per-lane partial row sums
  const u16* kb0 = k + (size_t)(bb * 2048) * 512 + h * 64;
  // window-blocked V^T: elem (W, nn, pos) at ((bb*64+W)*512 + nn)*32 + pos
  const u16* vtw = vt + (size_t)bb * 1048576 + h * 2048;

  #define STAGE(nb, tt) do {                                                  \
    int sr0 = w * 16 + lrow;                                                  \
    const u16* ks0 = kb0 + (size_t)((tt) * 64 + sr0) * 512 + lchunk * 8;      \
    const u16* vs0 = vtw + (size_t)(2 * (tt) + (lchunk >> 2)) * 16384         \
                   + (size_t)sr0 * 32 + (lchunk & 3) * 8;                     \
    gload_lds16(ks0, &kls[nb][(w * 16) * 64]);                                \
    gload_lds16(ks0 + (size_t)8 * 512, &kls[nb][(w * 16 + 8) * 64]);          \
    gload_lds16(vs0, &vls[nb][(w * 16) * 64]);                                \
    gload_lds16(vs0 + 256, &vls[nb][(w * 16 + 8) * 64]);                      \
  } while (0)

  // QK^T of one K-tile into sdst[2][4] (S^T[key][q=l15], both q-groups)
  #define QKT(kbuf, sdst) do {                                                \
    _Pragma("unroll")                                                         \
    for (int kg = 0; kg < 4; ++kg) {                                          \
      int rb = (kg * 16 + l15) * 64;                                          \
      s16x8 ka = *(const s16x8*)&(kbuf)[rb + ((g ^ sw) << 3)];                \
      s16x8 kc = *(const s16x8*)&(kbuf)[rb + (((4 + g) ^ sw) << 3)];          \
      sdst[0][kg] = mfma16(ka, qf0a, zero);                                   \
      sdst[0][kg] = mfma16(kc, qf1a, sdst[0][kg]);                            \
      sdst[1][kg] = mfma16(ka, qf0b, zero);                                   \
      sdst[1][kg] = mfma16(kc, qf1b, sdst[1][kg]);                            \
    }                                                                         \
  } while (0)

  // exp2 + bf16-pack of s-regs -> pk, accumulate lsum
  #define SMAX(ssrc) do {                                                     \
    _Pragma("unroll")                                                         \
    for (int qg = 0; qg < 2; ++qg) {                                          \
      _Pragma("unroll")                                                       \
      for (int b2 = 0; b2 < 2; ++b2) {                                        \
        _Pragma("unroll")                                                     \
        for (int r = 0; r < 4; ++r) {                                         \
          float p0 = __builtin_amdgcn_exp2f(ssrc[qg][2 * b2][r]);             \
          float p1 = __builtin_amdgcn_exp2f(ssrc[qg][2 * b2 + 1][r]);         \
          lsum[qg] += p0 + p1;                                                \
          union { float f; unsigned u; } ua, ub;                              \
          ua.f = p0; ub.f = p1;                                               \
          pk[qg][b2].u32v[r] = __builtin_amdgcn_perm(ub.u, ua.u, 0x07060302u);\
        }                                                                     \
      }                                                                       \
    }                                                                         \
  } while (0)

  #define PVC(vbuf) do {                                                      \
    _Pragma("unroll")                                                         \
    for (int b2 = 0; b2 < 2; ++b2) {                                          \
      _Pragma("unroll")                                                       \
      for (int nf = 0; nf < 4; ++nf) {                                        \
        s16x8 vf = *(const s16x8*)                                            \
            &(vbuf)[(nf * 16 + l15) * 64 + ((((b2 << 2) | g) ^ sw) << 3)];    \
        oacc[0][nf] = mfma16(pk[0][b2].v8, vf, oacc[0][nf]);                  \
        oacc[1][nf] = mfma16(pk[1][b2].v8, vf, oacc[1][nf]);                  \
      }                                                                       \
    }                                                                         \
  } while (0)

  typedef union { s16x8 v8; unsigned u32v[4]; } pku;

  // At top of ITER(kt): outstanding = own loads of tiles kt+1,kt+2 (4 each).
  // vmcnt(4) -> tile kt+1 landed (kt+2 stays in flight). Tail: kt>=30 ->
  // only tile 31 outstanding -> vmcnt(0). STAGE(kt+3) overwrites slot
  // (kt-1)&3: its reads (V at iter kt-1) were consumed by MFMAs (compiler
  // lgkmcnt before use) before each wave's barrier arrival -> safe.
  #define ITER(kt, scur, snxt) do {                                           \
    if ((kt) < 30) asm volatile("s_waitcnt vmcnt(4)" ::: "memory");           \
    else           asm volatile("s_waitcnt vmcnt(0)" ::: "memory");           \
    __builtin_amdgcn_s_barrier();                                             \
    if ((kt) + 3 < 32) STAGE(((kt) + 3) & 3, (kt) + 3);                       \
    if ((kt) + 1 < 32) QKT(kls[((kt) + 1) & 3], snxt);                        \
    pku pk[2][2];                                                             \
    SMAX(scur);                                                               \
    PVC(vls[(kt) & 3]);                                                       \
  } while (0)

  STAGE(0, 0);                                 // tiles 0,1,2 in flight
  STAGE(1, 1);
  STAGE(2, 2);
  asm volatile("s_waitcnt vmcnt(8)" ::: "memory");   // tile 0 landed (own)
  __builtin_amdgcn_s_barrier();                      // -> landed for all waves
  f32x4 sA[2][4], sB[2][4];
  QKT(kls[0], sA);                             // prologue QK^T(0)

  for (int k2 = 0; k2 < 32; k2 += 2) {         // 2x unroll: sA/sB role swap
    ITER(k2, sA, sB);
    ITER(k2 + 1, sB, sA);
  }
  #undef ITER
  #undef PVC
  #undef SMAX
  #undef QKT
  #undef STAGE

  #pragma unroll
  for (int qg = 0; qg < 2; ++qg) {
    float ls = lsum[qg];
    ls += __shfl_xor(ls, 16);                  // reduce across g-groups
    ls += __shfl_xor(ls, 32);
    float linv = 1.0f / ls;                    // valid for q = l15
    size_t obase = (size_t)(bb * 2048 + qbase + qg * 16 + 4 * g) * 512
                 + h * 64 + l15;
    #pragma unroll
    for (int r = 0; r < 4; ++r) {
      float lr = __shfl(linv, 4 * g + r);      // fetch l for q = 4g+r
      #pragma unroll
      for (int nf = 0; nf < 4; ++nf)
        o[obase + (size_t)r * 512 + nf * 16] = f2b(oacc[qg][nf][r] * lr);
    }
  }
}

// ---------------- launch ----------------------------------------------------
extern "C" void kernel_launch(void* const* d_in, const int* in_sizes, int n_in,
                              void* d_out, int out_size, void* d_ws, size_t ws_size,
                              hipStream_t stream)
{
  const float* x     = (const float*)d_in[0];
  const float* ln1_a = (const float*)d_in[1];
  const float* ln1_b = (const float*)d_in[2];
  const float* ln2_a = (const float*)d_in[3];
  const float* ln2_b = (const float*)d_in[4];
  const float* wq = (const float*)d_in[5];
  const float* wk = (const float*)d_in[6];
  const float* wv = (const float*)d_in[7];
  const float* wo = (const float*)d_in[8];
  const float* w1 = (const float*)d_in[9];
  const float* b1 = (const float*)d_in[10];
  const float* w2 = (const float*)d_in[11];
  const float* b2 = (const float*)d_in[12];

  char* ws = (char*)d_ws;                       // needs 75 MB
  float* xn_f = (float*)(ws + (size_t)0);       // 16 MB  LN1 out fp32 (resid)
  float* h_f  = (float*)(ws + ((size_t)16 << 20)); // 16 MB h fp32
  u16* xn_b = (u16*)(ws + ((size_t)32 << 20));  // 8 MB  LN1 out bf16
  u16* q_b  = (u16*)(ws + ((size_t)40 << 20));  // 8 MB  (reused as hn)
  u16* k_b  = (u16*)(ws + ((size_t)48 << 20));  // 8 MB
  u16* vt_b = (u16*)(ws + ((size_t)56 << 20));  // 8 MB  V^T window-blocked
  u16* at_b = (u16*)(ws + ((size_t)64 << 20));  // 8 MB  (reused as ffn-mid)
  u16* wb   = (u16*)(ws + ((size_t)72 << 20));  // 3 MB  bf16 weights
  u16 *wkb = wb + 262144, *wvb = wb + 2 * 262144;
  u16 *wob = wb + 3 * 262144, *w1b = wb + 4 * 262144, *w2b = wb + 5 * 262144;
  u16* hn_b = q_b;   // q dead after attention
  u16* f_b  = at_b;  // attn dead after WO

  dim3 blk(256);
  dim3 g512(64, 4);
  cast_w<<<dim3(256, 6), blk, 0, stream>>>(wq, wk, wv, wo, w1, w2, wb);
  ln_kernel<1, 1><<<dim3(2048), blk, 0, stream>>>(x, ln1_a, ln1_b, xn_f, xn_b);
  // QKV split, launched V -> K -> Q (same order as R7-R10 for attribution)
  // q pre-scaled by (1/sqrt(64))*log2(e) so attn computes p = exp2(s) directly
  gemm128<128><<<g512, blk, 0, stream>>>(
      xn_b, wvb, nullptr, nullptr, nullptr, nullptr, vt_b, 0.0f);
  gemm128<16><<<g512, blk, 0, stream>>>(
      xn_b, wkb, nullptr, nullptr, nullptr, k_b, nullptr, 0.0f);
  gemm128<16 | 32><<<g512, blk, 0, stream>>>(
      xn_b, wb, nullptr, nullptr, nullptr, q_b, nullptr, 0.18033688f);
  attn_kernel<<<dim3(32, 16), blk, 0, stream>>>(q_b, k_b, vt_b, at_b);
  gemm128<4 | 8><<<g512, blk, 0, stream>>>(
      at_b, wob, nullptr, xn_f, h_f, nullptr, nullptr, 0.0f);
  ln_kernel<0, 1><<<dim3(2048), blk, 0, stream>>>(h_f, ln2_a, ln2_b, nullptr, hn_b);
  gemm128<1 | 2 | 16><<<g512, blk, 0, stream>>>(
      hn_b, w1b, b1, nullptr, nullptr, f_b, nullptr, 0.0f);
  gemm128<1 | 4 | 8><<<g512, blk, 0, stream>>>(
      f_b, w2b, b2, h_f, (float*)d_out, nullptr, nullptr, 0.0f);
}

// Round 12
// 129.667 us; speedup vs baseline: 1.1038x; 1.1038x over previous
//
#include <hip/hip_runtime.h>

// EncoderLayer: B=4, S=2048, D=512, H=8, HD=64. fp32 I/O, bf16 MFMA compute.
// M = B*S = 8192 tokens. GEMMs: [8192,512] = [8192,512] @ W[512,512]^T.

typedef short s16x8 __attribute__((ext_vector_type(8)));
typedef float f32x4 __attribute__((ext_vector_type(4)));
typedef unsigned short u16;
typedef u16 u16x4 __attribute__((ext_vector_type(4)));

__device__ __forceinline__ u16 f2b(float f) {          // fp32 -> bf16 RNE
  union { float f; unsigned u; } c; c.f = f;
  return (u16)((c.u + 0x7FFFu + ((c.u >> 16) & 1u)) >> 16);
}

__device__ __forceinline__ f32x4 mfma16(s16x8 a, s16x8 b, f32x4 c) {
  return __builtin_amdgcn_mfma_f32_16x16x32_bf16(a, b, c, 0, 0, 0);
}

// async global->LDS, 16B per lane; dest = wave-uniform base + lane*16
__device__ __forceinline__ void gload_lds16(const u16* g, u16* l) {
  __builtin_amdgcn_global_load_lds(
      (const __attribute__((address_space(1))) unsigned*)g,
      (__attribute__((address_space(3))) unsigned*)l, 16, 0, 0);
}

// ---------------- weight cast: 6 x [512x512] fp32 -> bf16 (contiguous dst) --
// R12: nt store REVERTED (R11: +13us -- QKV consumers rely on L2-resident
// weights; both nt probes (R10 A-input, R11 weights) regressed, killing the
// dirty-line theory family. QKV anomaly parked as characterized-unfixed.)
__global__ __launch_bounds__(256) void cast_w(
    const float* __restrict__ s0, const float* __restrict__ s1,
    const float* __restrict__ s2, const float* __restrict__ s3,
    const float* __restrict__ s4, const float* __restrict__ s5,
    u16* __restrict__ dst)
{
  int i = blockIdx.x * 256 + threadIdx.x;   // float4 index, 65536 per matrix
  const float* s;
  switch (blockIdx.y) {
    case 0: s = s0; break; case 1: s = s1; break; case 2: s = s2; break;
    case 3: s = s3; break; case 4: s = s4; break; default: s = s5; break;
  }
  float4 v = ((const float4*)s)[i];
  u16x4 o; o.x = f2b(v.x); o.y = f2b(v.y); o.z = f2b(v.z); o.w = f2b(v.w);
  *(u16x4*)(dst + (size_t)blockIdx.y * 262144 + (size_t)i * 4) = o;
}

// ---------------- LayerNorm (torch: unbiased var, a*(x-mean)/(std+eps)+b) ---
template<int OF, int OB>
__global__ __launch_bounds__(256) void ln_kernel(
    const float* __restrict__ x, const float* __restrict__ ga,
    const float* __restrict__ gbv, float* __restrict__ yf, u16* __restrict__ yb)
{
  int row = blockIdx.x * 4 + (threadIdx.x >> 6);   // one wave per row
  int lane = threadIdx.x & 63;
  size_t base = (size_t)row * 512 + lane * 8;
  const float4* xr = (const float4*)(x + base);
  float4 v0 = xr[0], v1 = xr[1];
  float s  = v0.x + v0.y + v0.z + v0.w + v1.x + v1.y + v1.z + v1.w;
  float ss = v0.x*v0.x + v0.y*v0.y + v0.z*v0.z + v0.w*v0.w
           + v1.x*v1.x + v1.y*v1.y + v1.z*v1.z + v1.w*v1.w;
  #pragma unroll
  for (int m = 1; m < 64; m <<= 1) { s += __shfl_xor(s, m); ss += __shfl_xor(ss, m); }
  float mean = s * (1.0f / 512.0f);
  float var  = fmaxf((ss - 512.0f * mean * mean) * (1.0f / 511.0f), 0.0f);
  float inv  = 1.0f / (sqrtf(var) + 1e-6f);
  const float4* ap = (const float4*)(ga + lane * 8);
  const float4* bp = (const float4*)(gbv + lane * 8);
  float4 a0 = ap[0], a1 = ap[1], b0 = bp[0], b1 = bp[1];
  float4 y0, y1;
  y0.x = (v0.x-mean)*inv*a0.x + b0.x;  y0.y = (v0.y-mean)*inv*a0.y + b0.y;
  y0.z = (v0.z-mean)*inv*a0.z + b0.z;  y0.w = (v0.w-mean)*inv*a0.w + b0.w;
  y1.x = (v1.x-mean)*inv*a1.x + b1.x;  y1.y = (v1.y-mean)*inv*a1.y + b1.y;
  y1.z = (v1.z-mean)*inv*a1.z + b1.z;  y1.w = (v1.w-mean)*inv*a1.w + b1.w;
  if (OF) { float4* o = (float4*)(yf + base); o[0] = y0; o[1] = y1; }
  if (OB) {
    union { s16x8 v; u16 u[8]; } pk;
    pk.u[0]=f2b(y0.x); pk.u[1]=f2b(y0.y); pk.u[2]=f2b(y0.z); pk.u[3]=f2b(y0.w);
    pk.u[4]=f2b(y1.x); pk.u[5]=f2b(y1.y); pk.u[6]=f2b(y1.z); pk.u[7]=f2b(y1.w);
    *(s16x8*)(yb + base) = pk.v;
  }
}

// ---------------- GEMM 128x128 tile, BK=64 (8 K-iterations) -----------------
// 4 waves (2x2), each owns 64x64. LDS: 2 x (16KB A + 16KB B), 1 block/CU.
// Row = 8 chunks of 8 u16; swizzle chunk ^= (row&7) on staging source +
// ds_read (2-way = free). V^T epilogue window-blocked [B*W][nn][32]
// (W = sidx/32): one wave store instruction = 1KB contiguous.
// MODE bits: 1=bias, 2=relu, 4=resid(fp32), 8=store f32, 16=store bf16,
//            32=scale by qscale before bf16 store, 128=V^T window epilogue
template<int MODE>
__global__ __launch_bounds__(256) void gemm128(
    const u16* __restrict__ A, const u16* __restrict__ W,
    const float* __restrict__ bias, const float* __restrict__ resid,
    float* __restrict__ outf, u16* __restrict__ outb,
    u16* __restrict__ outb3, float qscale)
{
  __shared__ u16 als[2][128 * 64];             // 16KB per buf
  __shared__ u16 bls[2][128 * 64];
  int t = threadIdx.x, lane = t & 63, w = t >> 6;
  int l15 = lane & 15, g = lane >> 4;
  int wr = w >> 1, wc = w & 1;
  int mbase = blockIdx.x * 128, nbase = blockIdx.y * 128;

  // staging: instr j covers slots [j*256, j*256+256); slot cid -> row=cid>>3,
  // phys chunk cid&7, source (logical) chunk = (cid&7) ^ (row&7)
  size_t offA[4], offB[4];
  #pragma unroll
  for (int j = 0; j < 4; ++j) {
    int cid = j * 256 + t;
    int row = cid >> 3, cs = (cid & 7) ^ (row & 7);
    offA[j] = (size_t)(mbase + row) * 512 + cs * 8;
    offB[j] = (size_t)(nbase + row) * 512 + cs * 8;
  }

  #define GSTAGE(buf, k0) do {                                        \
    _Pragma("unroll")                                                 \
    for (int j = 0; j < 4; ++j)                                       \
      gload_lds16(A + (k0) + offA[j], &als[buf][(j * 256 + w * 64) * 8]); \
    _Pragma("unroll")                                                 \
    for (int j = 0; j < 4; ++j)                                       \
      gload_lds16(W + (k0) + offB[j], &bls[buf][(j * 256 + w * 64) * 8]); \
  } while (0)

  // fragment ds_read offsets (u16 units): row rA, logical chunk kh*4+g,
  // phys chunk = logical ^ (rA&7)
  int ar[4][2], br[4][2];
  #pragma unroll
  for (int i = 0; i < 4; ++i) {
    int rA = wr * 64 + i * 16 + l15;
    int rB = wc * 64 + i * 16 + l15;
    #pragma unroll
    for (int kh = 0; kh < 2; ++kh) {
      ar[i][kh] = rA * 64 + (((kh * 4 + g) ^ (rA & 7)) << 3);
      br[i][kh] = rB * 64 + (((kh * 4 + g) ^ (rB & 7)) << 3);
    }
  }

  f32x4 zero = {0.0f, 0.0f, 0.0f, 0.0f};
  f32x4 acc[4][4];
  #pragma unroll
  for (int mi = 0; mi < 4; ++mi)
    #pragma unroll
    for (int ni = 0; ni < 4; ++ni) acc[mi][ni] = zero;

  GSTAGE(0, 0);
  __syncthreads();
  int cur = 0;
  for (int kk = 0; kk < 8; ++kk) {
    if (kk < 7) GSTAGE(cur ^ 1, (kk + 1) * 64);    // prefetch next K-tile
    s16x8 af[4][2], bfr[4][2];
    #pragma unroll
    for (int i = 0; i < 4; ++i) {
      #pragma unroll
      for (int kh = 0; kh < 2; ++kh) {
        af[i][kh]  = *(const s16x8*)&als[cur][ar[i][kh]];
        bfr[i][kh] = *(const s16x8*)&bls[cur][br[i][kh]];
      }
    }
    #pragma unroll
    for (int kh = 0; kh < 2; ++kh)
      #pragma unroll
      for (int mi = 0; mi < 4; ++mi)
        #pragma unroll
        for (int ni = 0; ni < 4; ++ni)
          acc[mi][ni] = mfma16(af[mi][kh], bfr[ni][kh], acc[mi][ni]);
    __syncthreads();                               // prefetch landed, reads done
    cur ^= 1;
  }
  #undef GSTAGE

  if (MODE & 128) {
    // ---- V^T window-blocked epilogue: addr = ((b*64+W)*512+nn)*32 + pos ----
    // pos = 8g + 2r + (mi&1); one wave instruction = 1KB contiguous, 1 page.
    int bidx = mbase >> 11;
    int Wbase = ((mbase & 2047) >> 5) + wr * 2;    // window of sidx = m&2047
    #pragma unroll
    for (int ni = 0; ni < 4; ++ni) {
      int nn = nbase + wc * 64 + ni * 16 + l15;
      #pragma unroll
      for (int p = 0; p < 2; ++p) {            // mi-pair (2p, 2p+1)
        union { s16x8 v; u16 u[8]; } pkv;
        #pragma unroll
        for (int r = 0; r < 4; ++r) {
          pkv.u[2 * r]     = f2b(acc[2 * p][ni][r]);
          pkv.u[2 * r + 1] = f2b(acc[2 * p + 1][ni][r]);
        }
        *(s16x8*)(outb3 + ((size_t)((bidx * 64 + Wbase + p) * 512 + nn)) * 32
                  + 8 * g) = pkv.v;
      }
    }
  } else {
    #pragma unroll
    for (int ni = 0; ni < 4; ++ni) {
      int n = nbase + wc * 64 + ni * 16 + l15;
      float bv = (MODE & 1) ? bias[n] : 0.0f;
      #pragma unroll
      for (int mi = 0; mi < 4; ++mi) {
        #pragma unroll
        for (int r = 0; r < 4; ++r) {
          int m = mbase + wr * 64 + mi * 16 + 4 * g + r;  // D: col=l15, row=4g+r
          float v = acc[mi][ni][r] + bv;
          if (MODE & 2) v = fmaxf(v, 0.0f);
          if (MODE & 4) v += resid[(size_t)m * 512 + n];
          if (MODE & 8) outf[(size_t)m * 512 + n] = v;
          if (MODE & 16) {
            float vs = (MODE & 32) ? v * qscale : v;
            outb[(size_t)m * 512 + n] = f2b(vs);
          }
        }
      }
    }
  }
}

// ---------------- flash attention: QK^T-ahead software pipeline -------------
// 1 block = 128 q rows of one (b,h); 4 waves x 32 q rows (2 x 16-row frags).
// KVTILE=64. QK^T(kt+1) computed in the same scheduling region as
// softmax(kt)+PV(kt) so trans/LDS/MFMA overlap. 4 LDS buffers, 2-deep
// counted vmcnt prefetch. V staged from the window-blocked layout.
// R12: lsum computed on the MATRIX pipe via mfma(pk, ones) -- replaces 32
// VALU adds/wave-iter + the end shuffle-reduce + the per-r __shfl fetch.
// lsacc[qg][r] = full row-sum of (truncated-bf16) P for q row 4g+r, exact
// same P values that multiply V -> denominator consistent with numerator.
// Swapped QK^T: mfma(K,Q) -> P lane-local in PV A-frag layout; no online max
// (q pre-scaled by 0.125*log2e, |s|<~2 in log2 domain, exp2 overflow at 127).
__global__ __launch_bounds__(256) void attn_kernel(
    const u16* __restrict__ q, const u16* __restrict__ k,
    const u16* __restrict__ vt, u16* __restrict__ o)
{
  __shared__ u16 kls[4][64 * 64];              // 8KB per buf, 64KB total
  __shared__ u16 vls[4][64 * 64];
  int t = threadIdx.x, lane = t & 63, w = t >> 6;
  int l15 = lane & 15, g = lane >> 4;
  int sw = l15 & 7;                            // ds_read swizzle key
  int lrow = lane >> 3;                        // staging: local row 0..7
  int lchunk = (lane & 7) ^ (lrow & 7);        // staging: pre-swizzled chunk
  // XCD-aware remap: each XCD sees 4 (b,h) pairs -> K/V L2-resident
  int fid = blockIdx.x + 32 * blockIdx.y;      // 0..511
  int xcd = fid & 7, rest = fid >> 3;
  int bh = xcd * 4 + (rest & 3);
  int qt = rest >> 2;                          // 0..15, q-tile of 128
  int bb = bh >> 3, h = bh & 7;
  int qbase = qt * 128 + w * 32;

  const u16* qp = q + (size_t)(bb * 2048 + qbase + l15) * 512 + h * 64 + g * 8;
  s16x8 qf0a = *(const s16x8*)qp;              // B-frag: lane&15 = q row
  s16x8 qf1a = *(const s16x8*)(qp + 32);
  s16x8 qf0b = *(const s16x8*)(qp + 16 * 512); // q-group 1: rows +16
  s16x8 qf1b = *(const s16x8*)(qp + 16 * 512 + 32);
  f32x4 zero = {0.0f, 0.0f, 0.0f, 0.0f};
  const short one_bf16 = (short)0x3F80;        // bf16 1.0
  const s16x8 ones8 = {one_bf16, one_bf16, one_bf16, one_bf16,
                       one_bf16, one_bf16, one_bf16, one_bf16};
  f32x4 oacc[2][4];
  f32x4 lsacc[2];                              // row-sum acc (MFMA ones-trick)
  #pragma unroll
  for (int qg = 0; qg < 2; ++qg) {
    lsacc[qg] = zero;
    #pragma unroll
    for (int nf = 0; nf < 4; ++nf) oacc[qg][nf] = zero;
  }
  const u16* kb0 = k + (size_t)(bb * 2048) * 512 + h * 64;
  // window-blocked V^T: elem (W, nn, pos) at ((bb*64+W)*512 + nn)*32 + pos
  const u16* vtw = vt + (size_t)bb * 1048576 + h * 2048;

  #define STAGE(nb, tt) do {                                                  \
    int sr0 = w * 16 + lrow;                                                  \
    const u16* ks0 = kb0 + (size_t)((tt) * 64 + sr0) * 512 + lchunk * 8;      \
    const u16* vs0 = vtw + (size_t)(2 * (tt) + (lchunk >> 2)) * 16384         \
                   + (size_t)sr0 * 32 + (lchunk & 3) * 8;                     \
    gload_lds16(ks0, &kls[nb][(w * 16) * 64]);                                \
    gload_lds16(ks0 + (size_t)8 * 512, &kls[nb][(w * 16 + 8) * 64]);          \
    gload_lds16(vs0, &vls[nb][(w * 16) * 64]);                                \
    gload_lds16(vs0 + 256, &vls[nb][(w * 16 + 8) * 64]);                      \
  } while (0)

  // QK^T of one K-tile into sdst[2][4] (S^T[key][q=l15], both q-groups)
  #define QKT(kbuf, sdst) do {                                                \
    _Pragma("unroll")                                                         \
    for (int kg = 0; kg < 4; ++kg) {                                          \
      int rb = (kg * 16 + l15) * 64;                                          \
      s16x8 ka = *(const s16x8*)&(kbuf)[rb + ((g ^ sw) << 3)];                \
      s16x8 kc = *(const s16x8*)&(kbuf)[rb + (((4 + g) ^ sw) << 3)];          \
      sdst[0][kg] = mfma16(ka, qf0a, zero);                                   \
      sdst[0][kg] = mfma16(kc, qf1a, sdst[0][kg]);                            \
      sdst[1][kg] = mfma16(ka, qf0b, zero);                                   \
      sdst[1][kg] = mfma16(kc, qf1b, sdst[1][kg]);                            \
    }                                                                         \
  } while (0)

  // exp2 + bf16-pack of s-regs -> pk (lsum now via MFMA in PVC)
  #define SMAX(ssrc) do {                                                     \
    _Pragma("unroll")                                                         \
    for (int qg = 0; qg < 2; ++qg) {                                          \
      _Pragma("unroll")                                                       \
      for (int b2 = 0; b2 < 2; ++b2) {                                        \
        _Pragma("unroll")                                                     \
        for (int r = 0; r < 4; ++r) {                                         \
          float p0 = __builtin_amdgcn_exp2f(ssrc[qg][2 * b2][r]);             \
          float p1 = __builtin_amdgcn_exp2f(ssrc[qg][2 * b2 + 1][r]);         \
          union { float f; unsigned u; } ua, ub;                              \
          ua.f = p0; ub.f = p1;                                               \
          pk[qg][b2].u32v[r] = __builtin_amdgcn_perm(ub.u, ua.u, 0x07060302u);\
        }                                                                     \
      }                                                                       \
    }                                                                         \
  } while (0)

  #define PVC(vbuf) do {                                                      \
    _Pragma("unroll")                                                         \
    for (int b2 = 0; b2 < 2; ++b2) {                                          \
      lsacc[0] = mfma16(pk[0][b2].v8, ones8, lsacc[0]);                       \
      lsacc[1] = mfma16(pk[1][b2].v8, ones8, lsacc[1]);                       \
      _Pragma("unroll")                                                       \
      for (int nf = 0; nf < 4; ++nf) {                                        \
        s16x8 vf = *(const s16x8*)                                            \
            &(vbuf)[(nf * 16 + l15) * 64 + ((((b2 << 2) | g) ^ sw) << 3)];    \
        oacc[0][nf] = mfma16(pk[0][b2].v8, vf, oacc[0][nf]);                  \
        oacc[1][nf] = mfma16(pk[1][b2].v8, vf, oacc[1][nf]);                  \
      }                                                                       \
    }                                                                         \
  } while (0)

  typedef union { s16x8 v8; unsigned u32v[4]; } pku;

  // At top of ITER(kt): outstanding = own loads of tiles kt+1,kt+2 (4 each).
  // vmcnt(4) -> tile kt+1 landed (kt+2 stays in flight). Tail: kt>=30 ->
  // only tile 31 outstanding -> vmcnt(0). STAGE(kt+3) overwrites slot
  // (kt-1)&3: its reads (V at iter kt-1) were consumed by MFMAs (compiler
  // lgkmcnt before use) before each wave's barrier arrival -> safe.
  #define ITER(kt, scur, snxt) do {                                           \
    if ((kt) < 30) asm volatile("s_waitcnt vmcnt(4)" ::: "memory");           \
    else           asm volatile("s_waitcnt vmcnt(0)" ::: "memory");           \
    __builtin_amdgcn_s_barrier();                                             \
    if ((kt) + 3 < 32) STAGE(((kt) + 3) & 3, (kt) + 3);                       \
    if ((kt) + 1 < 32) QKT(kls[((kt) + 1) & 3], snxt);                        \
    pku pk[2][2];                                                             \
    SMAX(scur);                                                               \
    PVC(vls[(kt) & 3]);                                                       \
  } while (0)

  STAGE(0, 0);                                 // tiles 0,1,2 in flight
  STAGE(1, 1);
  STAGE(2, 2);
  asm volatile("s_waitcnt vmcnt(8)" ::: "memory");   // tile 0 landed (own)
  __builtin_amdgcn_s_barrier();                      // -> landed for all waves
  f32x4 sA[2][4], sB[2][4];
  QKT(kls[0], sA);                             // prologue QK^T(0)

  for (int k2 = 0; k2 < 32; k2 += 2) {         // 2x unroll: sA/sB role swap
    ITER(k2, sA, sB);
    ITER(k2 + 1, sB, sA);
  }
  #undef ITER
  #undef PVC
  #undef SMAX
  #undef QKT
  #undef STAGE

  // lsacc[qg][r] = full P row-sum for q row (qbase + qg*16 + 4g + r), valid
  // at every lane (ones-B makes all 16 output cols identical) -> no shfl.
  #pragma unroll
  for (int qg = 0; qg < 2; ++qg) {
    size_t obase = (size_t)(bb * 2048 + qbase + qg * 16 + 4 * g) * 512
                 + h * 64 + l15;
    #pragma unroll
    for (int r = 0; r < 4; ++r) {
      float lr = 1.0f / lsacc[qg][r];
      #pragma unroll
      for (int nf = 0; nf < 4; ++nf)
        o[obase + (size_t)r * 512 + nf * 16] = f2b(oacc[qg][nf][r] * lr);
    }
  }
}

// ---------------- launch ----------------------------------------------------
extern "C" void kernel_launch(void* const* d_in, const int* in_sizes, int n_in,
                              void* d_out, int out_size, void* d_ws, size_t ws_size,
                              hipStream_t stream)
{
  const float* x     = (const float*)d_in[0];
  const float* ln1_a = (const float*)d_in[1];
  const float* ln1_b = (const float*)d_in[2];
  const float* ln2_a = (const float*)d_in[3];
  const float* ln2_b = (const float*)d_in[4];
  const float* wq = (const float*)d_in[5];
  const float* wk = (const float*)d_in[6];
  const float* wv = (const float*)d_in[7];
  const float* wo = (const float*)d_in[8];
  const float* w1 = (const float*)d_in[9];
  const float* b1 = (const float*)d_in[10];
  const float* w2 = (const float*)d_in[11];
  const float* b2 = (const float*)d_in[12];

  char* ws = (char*)d_ws;                       // needs 75 MB
  float* xn_f = (float*)(ws + (size_t)0);       // 16 MB  LN1 out fp32 (resid)
  float* h_f  = (float*)(ws + ((size_t)16 << 20)); // 16 MB h fp32
  u16* xn_b = (u16*)(ws + ((size_t)32 << 20));  // 8 MB  LN1 out bf16
  u16* q_b  = (u16*)(ws + ((size_t)40 << 20));  // 8 MB  (reused as hn)
  u16* k_b  = (u16*)(ws + ((size_t)48 << 20));  // 8 MB
  u16* vt_b = (u16*)(ws + ((size_t)56 << 20));  // 8 MB  V^T window-blocked
  u16* at_b = (u16*)(ws + ((size_t)64 << 20));  // 8 MB  (reused as ffn-mid)
  u16* wb   = (u16*)(ws + ((size_t)72 << 20));  // 3 MB  bf16 weights
  u16 *wkb = wb + 262144, *wvb = wb + 2 * 262144;
  u16 *wob = wb + 3 * 262144, *w1b = wb + 4 * 262144, *w2b = wb + 5 * 262144;
  u16* hn_b = q_b;   // q dead after attention
  u16* f_b  = at_b;  // attn dead after WO

  dim3 blk(256);
  dim3 g512(64, 4);
  cast_w<<<dim3(256, 6), blk, 0, stream>>>(wq, wk, wv, wo, w1, w2, wb);
  ln_kernel<1, 1><<<dim3(2048), blk, 0, stream>>>(x, ln1_a, ln1_b, xn_f, xn_b);
  // QKV split, launched V -> K -> Q (same order as R7-R11 for attribution)
  // q pre-scaled by (1/sqrt(64))*log2(e) so attn computes p = exp2(s) directly
  gemm128<128><<<g512, blk, 0, stream>>>(
      xn_b, wvb, nullptr, nullptr, nullptr, nullptr, vt_b, 0.0f);
  gemm128<16><<<g512, blk, 0, stream>>>(
      xn_b, wkb, nullptr, nullptr, nullptr, k_b, nullptr, 0.0f);
  gemm128<16 | 32><<<g512, blk, 0, stream>>>(
      xn_b, wb, nullptr, nullptr, nullptr, q_b, nullptr, 0.18033688f);
  attn_kernel<<<dim3(32, 16), blk, 0, stream>>>(q_b, k_b, vt_b, at_b);
  gemm128<4 | 8><<<g512, blk, 0, stream>>>(
      at_b, wob, nullptr, xn_f, h_f, nullptr, nullptr, 0.0f);
  ln_kernel<0, 1><<<dim3(2048), blk, 0, stream>>>(h_f, ln2_a, ln2_b, nullptr, hn_b);
  gemm128<1 | 2 | 16><<<g512, blk, 0, stream>>>(
      hn_b, w1b, b1, nullptr, nullptr, f_b, nullptr, 0.0f);
  gemm128<1 | 4 | 8><<<g512, blk, 0, stream>>>(
      f_b, w2b, b2, h_f, (float*)d_out, nullptr, nullptr, 0.0f);
}